// Round 17
// baseline (281.101 us; speedup 1.0000x reference)
//
#include <hip/hip_runtime.h>

#define NE 19
#define CIN 64
#define Z1T_STRIDE 80          // bytes per Z1T row (32 bf16 of 40); 16B-aligned, 2-way banks = free
#define SLICE 5120             // per-graph Z1T slice (64*80)
#define NFRAG 18               // frag groups: 0-7 Wrel, 8-15 Wroot, 16-17 A-mix
#define FLAG_OFF 18432         // ws byte offset of the 18 release flags
#define MAGIC 0x5A17C3E9u

typedef float f32x4 __attribute__((ext_vector_type(4)));
typedef __bf16 bf16x4 __attribute__((ext_vector_type(4)));
typedef __bf16 bf16x8 __attribute__((ext_vector_type(8)));

// Native casts -> v_cvt_pk_bf16_f32 (1 instr / 2 values)
__device__ __forceinline__ bf16x8 packW(const float* q) {
  f32x4 a = *(const f32x4*)q;
  f32x4 b = *(const f32x4*)(q + 4);
  bf16x8 h;
  h[0]=(__bf16)a[0]; h[1]=(__bf16)a[1]; h[2]=(__bf16)a[2]; h[3]=(__bf16)a[3];
  h[4]=(__bf16)b[0]; h[5]=(__bf16)b[1]; h[6]=(__bf16)b[2]; h[7]=(__bf16)b[3];
  return h;
}

// Single kernel. 2048 single-wave blocks, ALL co-resident (8 blocks/CU needed,
// 15 fit by LDS) -> flag spin-wait is deadlock-free. Blocks 0..17 build one
// frag group each into ws, then release a flag; everyone else spins AFTER
// issuing x prefetches (prep hides under x HBM latency). Replay-safe: flags
// are poisoned 0xAA before timing; rewrites store byte-identical values.
// out = A@(X@Wrel^T) + X@Wroot^T + bias, all compute in MFMA, zero barriers.
// launch_bounds (64,2): VGPR cap 128 (cap = 256/min_waves; >=4 clamps to 64
// and spills — R12).
__global__ __launch_bounds__(64, 2) void gconv_kernel(
    const float* __restrict__ x, const float* __restrict__ ew,
    const float* __restrict__ Wrel, const float* __restrict__ Wroot,
    const float* __restrict__ bias, float* __restrict__ out,
    unsigned char* __restrict__ ws)
{
  __shared__ __align__(16) unsigned char sl[2 * SLICE];  // 10240 B

  const int lane = threadIdx.x & 63;
  const int g0 = blockIdx.x * 4;
  const int lr = lane & 15, hg = lane >> 4;
  const bf16x8* frB = (const bf16x8*)ws;
  unsigned int* flags = (unsigned int*)(ws + FLAG_OFF);

  // ---- (1) issue x prefetch for the first two graphs (HBM latency starts now)
  auto LOADAF = [&](bf16x8 af[2][2], int g) {
    const float* xg = x + (long long)g * NE * CIN;
    #pragma unroll
    for (int mt = 0; mt < 2; ++mt) {
      int rr = mt * 16 + lr; if (rr > NE - 1) rr = NE - 1;  // dup rows, stores guarded
      const float* xr = xg + rr * CIN + hg * 8;
      #pragma unroll
      for (int kt = 0; kt < 2; ++kt) af[mt][kt] = packW(xr + kt * 32);
    }
  };
  bf16x8 afa[2][2], afb[2][2];
  LOADAF(afa, g0);
  LOADAF(afb, g0 + 1);

  // ---- (2) distributed prep: block f < 18 builds frag group f
  if (blockIdx.x < NFRAG) {
    const int f = blockIdx.x;
    bf16x8 h;
    if (f < 16) {
      // Wc B-frag: group f = (p*8 + kt*4 + nt); p0=Wrel, p1=Wroot
      int p = f >> 3, kt = (f >> 2) & 1, nt = f & 3;
      const float* Wsrc = p ? Wroot : Wrel;
      h = packW(Wsrc + (nt * 16 + lr) * CIN + kt * 32 + hg * 8);
    } else {
      // A-mix A-frag: lane holds A[(f-16)*16+lr][k=hg*8+b], A[i][j]=sp(ew[j*19+i])
      int row = (f - 16) * 16 + lr;
      #pragma unroll
      for (int b = 0; b < 8; ++b) {
        int k = hg * 8 + b;
        float v = 0.0f;
        if (row < NE && k < NE) {
          float z = ew[k * NE + row];
          v = fmaxf(z, 0.0f) + log1pf(expf(-fabsf(z)));
        }
        h[b] = (__bf16)v;
      }
    }
    *(bf16x8*)(ws + (f * 64 + lane) * 16) = h;
    __threadfence();           // drain the frag store device-visibly
    if (lane == 0)
      __hip_atomic_store(&flags[f], MAGIC, __ATOMIC_RELEASE, __HIP_MEMORY_SCOPE_AGENT);
  }

  // ---- (3) wait for all frag groups (acquire -> L1-safe frag reads below)
  #pragma unroll 1
  for (int b = 0; b < NFRAG; ++b)
    while (__hip_atomic_load(&flags[b], __ATOMIC_ACQUIRE, __HIP_MEMORY_SCOPE_AGENT) != MAGIC)
      __builtin_amdgcn_s_sleep(2);

  // ---- (4) load frags once per wave
  bf16x8 bfa[8], bfb[8];
  #pragma unroll
  for (int i = 0; i < 8; ++i) bfa[i] = frB[i * 64 + lane];
  #pragma unroll
  for (int i = 0; i < 8; ++i) bfb[i] = frB[(8 + i) * 64 + lane];
  const bf16x8 afm0 = frB[1024 + lane];
  const bf16x8 afm1 = frB[1088 + lane];
  float biasv[4];
  #pragma unroll
  for (int nt = 0; nt < 4; ++nt) biasv[nt] = bias[nt * 16 + lr];

  // ---- (5) per-graph pipeline: half1 -> Z1T -> half2 -> mix -> DIRECT store
  auto PROC = [&](bf16x8 af[2][2], unsigned char* z1, int g) {
    // half 1: Z1 = X @ Wrel^T
    f32x4 zacc[2][4];
    #pragma unroll
    for (int mt = 0; mt < 2; ++mt)
      #pragma unroll
      for (int nt = 0; nt < 4; ++nt) { zacc[mt][nt][0]=0.f; zacc[mt][nt][1]=0.f; zacc[mt][nt][2]=0.f; zacc[mt][nt][3]=0.f; }
    #pragma unroll
    for (int nt = 0; nt < 4; ++nt)
      #pragma unroll
      for (int mt = 0; mt < 2; ++mt) {
        zacc[mt][nt] = __builtin_amdgcn_mfma_f32_16x16x32_bf16(
            af[mt][0], bfa[nt], zacc[mt][nt], 0, 0, 0);
        zacc[mt][nt] = __builtin_amdgcn_mfma_f32_16x16x32_bf16(
            af[mt][1], bfa[4 + nt], zacc[mt][nt], 0, 0, 0);
      }
    // bounce Z1 -> Z1T[c][j] bf16 (j 19..31 zeroed), 8 ds_write_b64
    #pragma unroll
    for (int nt = 0; nt < 4; ++nt) {
      int c = nt * 16 + lr;
      bf16x4 h0;
      #pragma unroll
      for (int b = 0; b < 4; ++b) h0[b] = (__bf16)zacc[0][nt][b];
      *(bf16x4*)(z1 + c * Z1T_STRIDE + hg * 8) = h0;
      bf16x4 h1;
      #pragma unroll
      for (int b = 0; b < 4; ++b) {
        int j = 16 + hg * 4 + b;
        h1[b] = (j < NE) ? (__bf16)zacc[1][nt][b] : (__bf16)0.0f;
      }
      *(bf16x4*)(z1 + c * Z1T_STRIDE + 32 + hg * 8) = h1;
    }

    // half 2: acc = X @ Wroot^T (independent of the bounce -> overlaps it)
    f32x4 acc[2][4];
    #pragma unroll
    for (int mt = 0; mt < 2; ++mt)
      #pragma unroll
      for (int nt = 0; nt < 4; ++nt) { acc[mt][nt][0]=0.f; acc[mt][nt][1]=0.f; acc[mt][nt][2]=0.f; acc[mt][nt][3]=0.f; }
    #pragma unroll
    for (int nt = 0; nt < 4; ++nt)
      #pragma unroll
      for (int mt = 0; mt < 2; ++mt) {
        acc[mt][nt] = __builtin_amdgcn_mfma_f32_16x16x32_bf16(
            af[mt][0], bfb[nt], acc[mt][nt], 0, 0, 0);
        acc[mt][nt] = __builtin_amdgcn_mfma_f32_16x16x32_bf16(
            af[mt][1], bfb[4 + nt], acc[mt][nt], 0, 0, 0);
      }
    // mix as MFMA: acc += A @ Z1
    #pragma unroll
    for (int nt = 0; nt < 4; ++nt) {
      bf16x8 zf = *(const bf16x8*)(z1 + (nt * 16 + lr) * Z1T_STRIDE + hg * 16);
      acc[0][nt] = __builtin_amdgcn_mfma_f32_16x16x32_bf16(afm0, zf, acc[0][nt], 0, 0, 0);
      acc[1][nt] = __builtin_amdgcn_mfma_f32_16x16x32_bf16(afm1, zf, acc[1][nt], 0, 0, 0);
    }
    // bias + DIRECT global stores: 16 lanes x 4B = 64B contiguous segments
    // (exact HBM granule) -> no write inflation, no LDS round-trip.
    float* og = out + (long long)g * NE * CIN;
    #pragma unroll
    for (int mt = 0; mt < 2; ++mt)
      #pragma unroll
      for (int nt = 0; nt < 4; ++nt)
        #pragma unroll
        for (int b = 0; b < 4; ++b) {
          int row = mt * 16 + hg * 4 + b;
          if (row < NE)
            og[row * CIN + nt * 16 + lr] = acc[mt][nt][b] + biasv[nt];
        }
  };

  // 4 graphs, lookahead-1 x prefetch; Z1T slices alternate (same-wave program
  // order makes slice reuse race-free).
  PROC(afa, sl,         g0);
  LOADAF(afa, g0 + 2);
  PROC(afb, sl + SLICE, g0 + 1);
  LOADAF(afb, g0 + 3);
  PROC(afa, sl,         g0 + 2);
  PROC(afb, sl + SLICE, g0 + 3);
}

extern "C" void kernel_launch(void* const* d_in, const int* in_sizes, int n_in,
                              void* d_out, int out_size, void* d_ws, size_t ws_size,
                              hipStream_t stream) {
  const float* x    = (const float*)d_in[0];
  const float* ew   = (const float*)d_in[1];
  const float* Wrel = (const float*)d_in[2];
  const float* Wroot= (const float*)d_in[3];
  const float* bias = (const float*)d_in[4];
  float* out = (float*)d_out;
  unsigned char* ws = (unsigned char*)d_ws;   // needs 18432 + 72 bytes

  const int ngraphs = (in_sizes[0] / CIN) / NE;   // 8192
  const int nblocks = ngraphs / 4;                // 2048 single-wave blocks
  gconv_kernel<<<nblocks, 64, 0, stream>>>(x, ew, Wrel, Wroot, bias, out, ws);
}

// Round 18
// 24.885 us; speedup vs baseline: 11.2960x; 11.2960x over previous
//
#include <hip/hip_runtime.h>

#define NE 19
#define CIN 64
#define Z1T_STRIDE 80          // bytes per Z1T row (32 bf16 of 40); 16B-aligned, 2-way banks = free
#define SLICE 5120             // per-graph Z1T slice (64*80)
#define WS_AFRAG 16384         // ws: [0,16K) Wc B-frags; [16K,18K) A-mix A-frags

typedef float f32x4 __attribute__((ext_vector_type(4)));
typedef __bf16 bf16x4 __attribute__((ext_vector_type(4)));
typedef __bf16 bf16x8 __attribute__((ext_vector_type(8)));

// Native casts -> v_cvt_pk_bf16_f32 (1 instr / 2 values)
__device__ __forceinline__ bf16x8 packW(const float* q) {
  f32x4 a = *(const f32x4*)q;
  f32x4 b = *(const f32x4*)(q + 4);
  bf16x8 h;
  h[0]=(__bf16)a[0]; h[1]=(__bf16)a[1]; h[2]=(__bf16)a[2]; h[3]=(__bf16)a[3];
  h[4]=(__bf16)b[0]; h[5]=(__bf16)b[1]; h[6]=(__bf16)b[2]; h[7]=(__bf16)b[3];
  return h;
}

// K1 (5 blocks): pack Wc B-frags + softplus(A) A-frags (bf16) into workspace.
// B-frag fid = ((p*2+kt)*4+nt)*64+lane, p0=Wrel p1=Wroot.
__global__ void prep_kernel(const float* __restrict__ ew,
                            const float* __restrict__ Wrel,
                            const float* __restrict__ Wroot,
                            unsigned char* __restrict__ ws) {
  const int t = threadIdx.x, bid = blockIdx.x;
  if (bid < 4) {
    int fid = bid * 256 + t;
    int p = fid >> 9, kt = (fid >> 8) & 1, nt = (fid >> 6) & 3, lane = fid & 63;
    const float* Wsrc = p ? Wroot : Wrel;
    *(bf16x8*)(ws + fid * 16) =
        packW(Wsrc + (nt * 16 + (lane & 15)) * CIN + kt * 32 + (lane >> 4) * 8);
  } else if (t < 128) {
    // A-mix A-frag: lane holds A[mt*16+(lane&15)][k=(lane>>4)*8+b], A[i][j]=sp(ew[j*19+i])
    int mt = t >> 6, lane = t & 63;
    int row = mt * 16 + (lane & 15);
    bf16x8 h;
    #pragma unroll
    for (int b = 0; b < 8; ++b) {
      int k = (lane >> 4) * 8 + b;
      float v = 0.0f;
      if (row < NE && k < NE) {
        float z = ew[k * NE + row];
        v = fmaxf(z, 0.0f) + log1pf(expf(-fabsf(z)));
      }
      h[b] = (__bf16)v;
    }
    *(bf16x8*)(ws + WS_AFRAG + t * 16) = h;
  }
}

// K2: single-wave blocks, 4 graphs/wave (lookahead-1 x prefetch), zero
// barriers, all compute in MFMA. Frags loaded ONCE per wave (R17: VGPR 88,
// fits). Direct 64B-segment global stores (R17: WRITE stays 38.9MB — no
// inflation), no LDS out-bounce. out = A@(X@Wrel^T) + X@Wroot^T + bias
// launch_bounds (64,2): VGPR cap 128 (cap = 256/min_waves; >=4 clamps to 64
// and spills — R12).
__global__ __launch_bounds__(64, 2) void gconv_kernel(
    const float* __restrict__ x, const float* __restrict__ bias,
    const unsigned char* __restrict__ ws, float* __restrict__ out)
{
  __shared__ __align__(16) unsigned char sl[2 * SLICE];  // 10240 B

  const int lane = threadIdx.x & 63;
  const int g0 = blockIdx.x * 4;
  const int lr = lane & 15, hg = lane >> 4;
  const bf16x8* frB = (const bf16x8*)ws;

  // ---- x prefetch for the first two graphs (HBM latency starts now)
  auto LOADAF = [&](bf16x8 af[2][2], int g) {
    const float* xg = x + (long long)g * NE * CIN;
    #pragma unroll
    for (int mt = 0; mt < 2; ++mt) {
      int rr = mt * 16 + lr; if (rr > NE - 1) rr = NE - 1;  // dup rows, stores guarded
      const float* xr = xg + rr * CIN + hg * 8;
      #pragma unroll
      for (int kt = 0; kt < 2; ++kt) af[mt][kt] = packW(xr + kt * 32);
    }
  };
  bf16x8 afa[2][2], afb[2][2];
  LOADAF(afa, g0);
  LOADAF(afb, g0 + 1);

  // ---- frags ONCE per wave (18 L2-hot loads; arrive under the x latency)
  bf16x8 bfa[8], bfb[8];
  #pragma unroll
  for (int i = 0; i < 8; ++i) bfa[i] = frB[i * 64 + lane];
  #pragma unroll
  for (int i = 0; i < 8; ++i) bfb[i] = frB[(8 + i) * 64 + lane];
  const bf16x8 afm0 = frB[1024 + lane];
  const bf16x8 afm1 = frB[1088 + lane];
  float biasv[4];
  #pragma unroll
  for (int nt = 0; nt < 4; ++nt) biasv[nt] = bias[nt * 16 + lr];

  // ---- per-graph pipeline: half1 -> Z1T -> half2 -> mix -> DIRECT store
  auto PROC = [&](bf16x8 af[2][2], unsigned char* z1, int g) {
    // half 1: Z1 = X @ Wrel^T
    f32x4 zacc[2][4];
    #pragma unroll
    for (int mt = 0; mt < 2; ++mt)
      #pragma unroll
      for (int nt = 0; nt < 4; ++nt) { zacc[mt][nt][0]=0.f; zacc[mt][nt][1]=0.f; zacc[mt][nt][2]=0.f; zacc[mt][nt][3]=0.f; }
    #pragma unroll
    for (int nt = 0; nt < 4; ++nt)
      #pragma unroll
      for (int mt = 0; mt < 2; ++mt) {
        zacc[mt][nt] = __builtin_amdgcn_mfma_f32_16x16x32_bf16(
            af[mt][0], bfa[nt], zacc[mt][nt], 0, 0, 0);
        zacc[mt][nt] = __builtin_amdgcn_mfma_f32_16x16x32_bf16(
            af[mt][1], bfa[4 + nt], zacc[mt][nt], 0, 0, 0);
      }
    // bounce Z1 -> Z1T[c][j] bf16 (j 19..31 zeroed), 8 ds_write_b64
    #pragma unroll
    for (int nt = 0; nt < 4; ++nt) {
      int c = nt * 16 + lr;
      bf16x4 h0;
      #pragma unroll
      for (int b = 0; b < 4; ++b) h0[b] = (__bf16)zacc[0][nt][b];
      *(bf16x4*)(z1 + c * Z1T_STRIDE + hg * 8) = h0;
      bf16x4 h1;
      #pragma unroll
      for (int b = 0; b < 4; ++b) {
        int j = 16 + hg * 4 + b;
        h1[b] = (j < NE) ? (__bf16)zacc[1][nt][b] : (__bf16)0.0f;
      }
      *(bf16x4*)(z1 + c * Z1T_STRIDE + 32 + hg * 8) = h1;
    }

    // half 2: acc = X @ Wroot^T (independent of the bounce -> overlaps it)
    f32x4 acc[2][4];
    #pragma unroll
    for (int mt = 0; mt < 2; ++mt)
      #pragma unroll
      for (int nt = 0; nt < 4; ++nt) { acc[mt][nt][0]=0.f; acc[mt][nt][1]=0.f; acc[mt][nt][2]=0.f; acc[mt][nt][3]=0.f; }
    #pragma unroll
    for (int nt = 0; nt < 4; ++nt)
      #pragma unroll
      for (int mt = 0; mt < 2; ++mt) {
        acc[mt][nt] = __builtin_amdgcn_mfma_f32_16x16x32_bf16(
            af[mt][0], bfb[nt], acc[mt][nt], 0, 0, 0);
        acc[mt][nt] = __builtin_amdgcn_mfma_f32_16x16x32_bf16(
            af[mt][1], bfb[4 + nt], acc[mt][nt], 0, 0, 0);
      }
    // mix as MFMA: acc += A @ Z1
    #pragma unroll
    for (int nt = 0; nt < 4; ++nt) {
      bf16x8 zf = *(const bf16x8*)(z1 + (nt * 16 + lr) * Z1T_STRIDE + hg * 16);
      acc[0][nt] = __builtin_amdgcn_mfma_f32_16x16x32_bf16(afm0, zf, acc[0][nt], 0, 0, 0);
      acc[1][nt] = __builtin_amdgcn_mfma_f32_16x16x32_bf16(afm1, zf, acc[1][nt], 0, 0, 0);
    }
    // bias + DIRECT global stores: 16 lanes x 4B = 64B contiguous segments
    // (R17 evidence: WRITE_SIZE stays 38.9MB — no inflation, no LDS trip)
    float* og = out + (long long)g * NE * CIN;
    #pragma unroll
    for (int mt = 0; mt < 2; ++mt)
      #pragma unroll
      for (int nt = 0; nt < 4; ++nt)
        #pragma unroll
        for (int b = 0; b < 4; ++b) {
          int row = mt * 16 + hg * 4 + b;
          if (row < NE)
            og[row * CIN + nt * 16 + lr] = acc[mt][nt][b] + biasv[nt];
        }
  };

  // 4 graphs, lookahead-1 x prefetch; Z1T slices alternate (same-wave program
  // order makes slice reuse race-free).
  PROC(afa, sl,         g0);
  LOADAF(afa, g0 + 2);
  PROC(afb, sl + SLICE, g0 + 1);
  LOADAF(afb, g0 + 3);
  PROC(afa, sl,         g0 + 2);
  PROC(afb, sl + SLICE, g0 + 3);
}

extern "C" void kernel_launch(void* const* d_in, const int* in_sizes, int n_in,
                              void* d_out, int out_size, void* d_ws, size_t ws_size,
                              hipStream_t stream) {
  const float* x    = (const float*)d_in[0];
  const float* ew   = (const float*)d_in[1];
  const float* Wrel = (const float*)d_in[2];
  const float* Wroot= (const float*)d_in[3];
  const float* bias = (const float*)d_in[4];
  float* out = (float*)d_out;
  unsigned char* ws = (unsigned char*)d_ws;   // needs 18432 B

  prep_kernel<<<5, 256, 0, stream>>>(ew, Wrel, Wroot, ws);

  const int ngraphs = (in_sizes[0] / CIN) / NE;   // 8192
  const int nblocks = ngraphs / 4;                // 2048 single-wave blocks
  gconv_kernel<<<nblocks, 64, 0, stream>>>(x, bias, ws, out);
}